// Round 18
// baseline (201.418 us; speedup 1.0000x reference)
//
#include <hip/hip_runtime.h>
#include <hip/hip_fp8.h>

typedef __attribute__((ext_vector_type(8))) short short8;
typedef __attribute__((ext_vector_type(4))) float floatx4;
typedef _Float16 half_t;
typedef unsigned short u16;
typedef unsigned char u8;
typedef unsigned int u32;
typedef unsigned long long u64;
typedef __attribute__((ext_vector_type(4))) unsigned short ushort4v;
typedef __attribute__((ext_vector_type(4))) u32 uint4v;

#define D_DIM 512
#define PD_DIM 128

// async global->LDS DMA, 16 B per lane. LDS dest = wave-uniform base + lane*16.
typedef __attribute__((address_space(3))) u32 lds_u32;
typedef const __attribute__((address_space(1))) u32 gbl_u32;
__device__ __forceinline__ void cp16(void* lds_base_wave_uniform, const void* g_per_lane){
#if __has_builtin(__builtin_amdgcn_global_load_lds)
  __builtin_amdgcn_global_load_lds((gbl_u32*)g_per_lane,
                                   (lds_u32*)lds_base_wave_uniform,
                                   16, 0, 0);
#else
  int lane = threadIdx.x & 63;
  ((float4*)lds_base_wave_uniform)[lane] = *(const float4*)((const char*)g_per_lane);
#endif
}

__device__ __forceinline__ u16 f2bf(float f){
  u32 u = __builtin_bit_cast(u32, f);
  u += 0x7fffu + ((u >> 16) & 1u);
  return (u16)(u >> 16);
}

__device__ __forceinline__ u8 f2fp8_sw(float f){
  __hip_fp8_e4m3 q(f);
  return (u8)q.__x;
}
__device__ __forceinline__ float fp82f(u8 b){
  __hip_fp8_e4m3 q;
  q.__x = (__hip_fp8_storage_t)b;
  return (float)q;
}

// HW packed f32->fp8(e4m3 OCP on gfx950): 2 instrs per 4 values.
__device__ __forceinline__ u32 pack4_fp8(float v0, float v1, float v2, float v3){
#if __has_builtin(__builtin_amdgcn_cvt_pk_fp8_f32)
  u32 r = 0;
  r = __builtin_amdgcn_cvt_pk_fp8_f32(v0, v1, r, false);  // bytes 0,1
  r = __builtin_amdgcn_cvt_pk_fp8_f32(v2, v3, r, true);   // bytes 2,3
  return r;
#else
  return (u32)f2fp8_sw(v0) | ((u32)f2fp8_sw(v1) << 8) |
         ((u32)f2fp8_sw(v2) << 16) | ((u32)f2fp8_sw(v3) << 24);
#endif
}

// fused f32->bf16 conversion for x (1048576 f4), w1 (65536 f4), w2 (16384 f4)
__global__ void cvt_all(const float* __restrict__ x, const float* __restrict__ w1,
                        const float* __restrict__ w2, u16* __restrict__ xb,
                        u16* __restrict__ w1b, u16* __restrict__ w2b){
  int i = blockIdx.x * blockDim.x + threadIdx.x;
  const float* s; u16* d; int off;
  if (i < 1048576)      { s = x;  d = xb;  off = i; }
  else if (i < 1114112) { s = w1; d = w1b; off = i - 1048576; }
  else if (i < 1130496) { s = w2; d = w2b; off = i - 1114112; }
  else return;
  float4 v = ((const float4*)s)[off];
  u16 o0 = f2bf(v.x), o1 = f2bf(v.y), o2 = f2bf(v.z), o3 = f2bf(v.w);
  ((u32*)d)[off*2]   = (u32)o0 | ((u32)o1 << 16);
  ((u32*)d)[off*2+1] = (u32)o2 | ((u32)o3 << 16);
}

// C[m,n] = relu(sum_k A[m,k]*B[n,k]) -> bf16. A:8192x512, B:512x512.
// 64x64 tile, BK=128, XOR-swizzled DMA staging (rounds 12/17).
__global__ __launch_bounds__(256) void gemm1_relu(const u16* __restrict__ A,
                                                  const u16* __restrict__ Bm,
                                                  u16* __restrict__ C){
  __shared__ __align__(16) u16 As[64*128];   // 16 KB (1024 chunks of 16 B)
  __shared__ __align__(16) u16 Bs[64*128];   // 16 KB
  int tid = threadIdx.x;
  int m0 = blockIdx.x * 64, n0 = blockIdx.y * 64;
  int w = tid >> 6, lane = tid & 63;
  int wy = w >> 1, wx = w & 1;               // wave tile: 32 x 32
  int mrow = lane & 15, kg = lane >> 4;
  floatx4 acc[2][2];
#pragma unroll
  for (int mt = 0; mt < 2; mt++)
#pragma unroll
    for (int nt = 0; nt < 2; nt++)
      acc[mt][nt] = (floatx4){0.f, 0.f, 0.f, 0.f};

  for (int k0 = 0; k0 < D_DIM; k0 += 128){
    __syncthreads();
#pragma unroll
    for (int i = 0; i < 4; i++){
      int c = tid + 256*i;
      int row = c >> 4, slot = c & 15;
      int gs = slot ^ (row & 7);
      cp16((char*)As + i*4096 + w*1024,
           (const char*)(A + (size_t)(m0+row)*D_DIM + k0) + gs*16);
      cp16((char*)Bs + i*4096 + w*1024,
           (const char*)(Bm + (size_t)(n0+row)*D_DIM + k0) + gs*16);
    }
    __syncthreads();
    int rx = mrow & 7;
#pragma unroll
    for (int s = 0; s < 4; s++){
      int lslot = (s*4 + kg) ^ rx;
      short8 af[2], bfr[2];
#pragma unroll
      for (int mt = 0; mt < 2; mt++)
        af[mt]  = *(const short8*)&As[(wy*32 + mt*16 + mrow)*128 + lslot*8];
#pragma unroll
      for (int nt = 0; nt < 2; nt++)
        bfr[nt] = *(const short8*)&Bs[(wx*32 + nt*16 + mrow)*128 + lslot*8];
#pragma unroll
      for (int mt = 0; mt < 2; mt++)
#pragma unroll
        for (int nt = 0; nt < 2; nt++)
          acc[mt][nt] = __builtin_amdgcn_mfma_f32_16x16x32_bf16(bfr[nt], af[mt], acc[mt][nt], 0, 0, 0);
    }
  }
#pragma unroll
  for (int mt = 0; mt < 2; mt++){
    int m = m0 + wy*32 + mt*16 + mrow;
#pragma unroll
    for (int nt = 0; nt < 2; nt++){
      int nchunk = n0 + wx*32 + nt*16 + kg*4;
      ushort4v pk;
#pragma unroll
      for (int i = 0; i < 4; i++){
        float v = acc[mt][nt][i];
        v = v > 0.f ? v : 0.f;
        pk[i] = f2bf(v);
      }
      *(ushort4v*)&C[(size_t)m*D_DIM + nchunk] = pk;
    }
  }
}

// Hn[m,:] = normalize(A[m,:] @ Bm^T) -> bf16. 32-row tiles, grid 256,
// BK=64 DMA+swizzle, Cs stride 132 (proven round 13).
__global__ __launch_bounds__(256) void gemm2_norm(const u16* __restrict__ A,
                                                  const u16* __restrict__ Bm,
                                                  u16* __restrict__ Hn){
  __shared__ __align__(16) char smem[20480];
  u16* As = (u16*)smem;            // 32 x 64 bf16 = 4 KB
  u16* Bs = (u16*)(smem + 4096);   // 128 x 64 bf16 = 16 KB
  float* Cs = (float*)smem;        // 32 x 132 f32 (reuse)
  int tid = threadIdx.x;
  int m0 = blockIdx.x * 32;
  int w = tid >> 6, lane = tid & 63;
  int wr = w & 1, wc = w >> 1;
  int mrow = lane & 15, kg = lane >> 4;
  floatx4 acc[4];
#pragma unroll
  for (int nt = 0; nt < 4; nt++) acc[nt] = (floatx4){0.f, 0.f, 0.f, 0.f};

  for (int k0 = 0; k0 < D_DIM; k0 += 64){
    __syncthreads();
    {
      int row = tid >> 3, slot = tid & 7;
      int gs = slot ^ (row & 7);
      cp16((char*)As + w*1024,
           (const char*)(A + (size_t)(m0+row)*D_DIM + k0) + gs*16);
    }
#pragma unroll
    for (int i = 0; i < 4; i++){
      int c = tid + 256*i;
      int row = c >> 3, slot = c & 7;
      int gs = slot ^ (row & 7);
      cp16((char*)Bs + i*4096 + w*1024,
           (const char*)(Bm + (size_t)row*D_DIM + k0) + gs*16);
    }
    __syncthreads();
    int rx = mrow & 7;
#pragma unroll
    for (int s = 0; s < 2; s++){
      int lslot = (s*4 + kg) ^ rx;
      short8 af = *(const short8*)&As[(wr*16 + mrow)*64 + lslot*8];
#pragma unroll
      for (int nt = 0; nt < 4; nt++){
        short8 bf8 = *(const short8*)&Bs[(wc*64 + nt*16 + mrow)*64 + lslot*8];
        acc[nt] = __builtin_amdgcn_mfma_f32_16x16x32_bf16(af, bf8, acc[nt], 0, 0, 0);
      }
    }
  }
  __syncthreads();
#pragma unroll
  for (int nt = 0; nt < 4; nt++){
    int cc = wc*64 + nt*16 + mrow;
#pragma unroll
    for (int i = 0; i < 4; i++)
      Cs[(wr*16 + kg*4 + i)*132 + cc] = acc[nt][i];
  }
  __syncthreads();
  int r = tid >> 3, seg = tid & 7;
  const float* rowp = Cs + r*132 + seg*16;
  float ssq = 0.f;
#pragma unroll
  for (int j = 0; j < 16; j++){ float v = rowp[j]; ssq += v*v; }
  ssq += __shfl_xor(ssq, 1);
  ssq += __shfl_xor(ssq, 2);
  ssq += __shfl_xor(ssq, 4);
  float rn = rsqrtf(fmaxf(ssq, 1e-24f));
  u32 pkw[8];
#pragma unroll
  for (int j = 0; j < 8; j++){
    float2 v = *(const float2*)(rowp + 2*j);
    pkw[j] = (u32)f2bf(v.x * rn) | ((u32)f2bf(v.y * rn) << 16);
  }
  u32* orow = (u32*)(Hn + (size_t)(m0 + r)*PD_DIM + seg*16);
  *(uint4v*)orow     = (uint4v){pkw[0], pkw[1], pkw[2], pkw[3]};
  *(uint4v*)(orow+4) = (uint4v){pkw[4], pkw[5], pkw[6], pkw[7]};
}

// S[m,n] = fp8_e4m3(2 * hn[m].hn[n]). REGISTER-DIRECT operands: K=128 means
// each A/B fragment is a contiguous 16-B slice of hn (per-lane load pattern
// proven in rounds 2/3); hn is 2 MB L2-resident with L1 reuse inside a block.
// Dropping the 64-KB operand LDS removes the staging DMA + both compute
// barriers and cuts LDS to the 17-KB epilogue buffer -> 4+ blocks/CU
// (round 17's 2/CU was the latency bottleneck). LDS round-trip epilogue
// (proven round 16) unchanged.
__global__ __launch_bounds__(256) void sim_gemm(const u16* __restrict__ A,
                                                u8* __restrict__ S){
  __shared__ __align__(16) u32 lb[128*33];   // 16.9 KB epilogue buffer
  int tid = threadIdx.x;
  int m0 = blockIdx.x * 128, n0 = blockIdx.y * 128;
  int w = tid >> 6, lane = tid & 63;
  int wy = w >> 1, wx = w & 1;
  int mrow = lane & 15, kg = lane >> 4;

  floatx4 acc[4][4];
#pragma unroll
  for (int mt = 0; mt < 4; mt++)
#pragma unroll
    for (int nt = 0; nt < 4; nt++)
      acc[mt][nt] = (floatx4){0.f, 0.f, 0.f, 0.f};

#pragma unroll
  for (int s = 0; s < 4; s++){
    short8 af[4], bfr[4];
#pragma unroll
    for (int mt = 0; mt < 4; mt++)
      af[mt]  = *(const short8*)(A + (size_t)(m0 + wy*64 + mt*16 + mrow)*PD_DIM + s*32 + kg*8);
#pragma unroll
    for (int nt = 0; nt < 4; nt++)
      bfr[nt] = *(const short8*)(A + (size_t)(n0 + wx*64 + nt*16 + mrow)*PD_DIM + s*32 + kg*8);
#pragma unroll
    for (int mt = 0; mt < 4; mt++)
#pragma unroll
      for (int nt = 0; nt < 4; nt++)
        acc[mt][nt] = __builtin_amdgcn_mfma_f32_16x16x32_bf16(bfr[nt], af[mt], acc[mt][nt], 0, 0, 0);
  }

  // epilogue: fp8 tile -> padded LDS (stride 33 u32/row) -> coalesced 128-B
  // row-segment stores (dwordx4 per lane)
#pragma unroll
  for (int mt = 0; mt < 4; mt++){
    int m = wy*64 + mt*16 + mrow;
#pragma unroll
    for (int nt = 0; nt < 4; nt++){
      int ncol = wx*16 + nt*4 + kg;
      u32 pk = pack4_fp8(acc[mt][nt][0] * 2.0f, acc[mt][nt][1] * 2.0f,
                         acc[mt][nt][2] * 2.0f, acc[mt][nt][3] * 2.0f);
      lb[m*33 + ncol] = pk;
    }
  }
  __syncthreads();
#pragma unroll
  for (int i = 0; i < 4; i++){
    int c = tid + 256*i;
    int row = c >> 3, off = c & 7;
    const u32* src = lb + row*33 + off*4;
    uint4v v = (uint4v){src[0], src[1], src[2], src[3]};
    *(uint4v*)&S[(size_t)(m0+row)*8192 + n0 + off*16] = v;
  }
}

// One run per block; anchor row (8 KB fp8) in LDS; partials to global.
__global__ __launch_bounds__(256) void pair_lse(const u8* __restrict__ S,
                                                const int* __restrict__ negs,
                                                float* __restrict__ partials){
  __shared__ __align__(16) u8 row[8192];
  __shared__ float red[4];
  int tid = threadIdx.x;
  int g = blockIdx.x;
  int c = g / 255, r = g - c*255;
  int a = c + 32*r;
  const float4* src = (const float4*)(S + (size_t)a*8192);
  float4* dst = (float4*)row;
#pragma unroll
  for (int i = 0; i < 2; i++) dst[tid + 256*i] = src[tid + 256*i];
  __syncthreads();

  int len = 255 - r;
  size_t start = (size_t)c*32640 + (size_t)(r*(511 - r))/2;
  float lsum = 0.f;
  if (tid < len){
    size_t p = start + tid;
    int poscol = c + 32*(r + 1 + tid);
    float lg[11];
    lg[0] = fp82f(row[poscol]);
    const int2* np = (const int2*)(negs + p*10);
    int2 n0 = np[0], n1 = np[1], n2 = np[2], n3 = np[3], n4 = np[4];
    lg[1]  = fp82f(row[n0.x]);  lg[2]  = fp82f(row[n0.y]);
    lg[3]  = fp82f(row[n1.x]);  lg[4]  = fp82f(row[n1.y]);
    lg[5]  = fp82f(row[n2.x]);  lg[6]  = fp82f(row[n2.y]);
    lg[7]  = fp82f(row[n3.x]);  lg[8]  = fp82f(row[n3.y]);
    lg[9]  = fp82f(row[n4.x]);  lg[10] = fp82f(row[n4.y]);
    float s = 0.f;
#pragma unroll
    for (int j = 0; j < 11; j++) s += __expf(lg[j]);
    lsum = __logf(s) - lg[0];
  }
  lsum += __shfl_xor(lsum, 1);
  lsum += __shfl_xor(lsum, 2);
  lsum += __shfl_xor(lsum, 4);
  lsum += __shfl_xor(lsum, 8);
  lsum += __shfl_xor(lsum, 16);
  lsum += __shfl_xor(lsum, 32);
  int wv = tid >> 6;
  if ((tid & 63) == 0) red[wv] = lsum;
  __syncthreads();
  if (tid == 0) partials[g] = red[0] + red[1] + red[2] + red[3];
}

__global__ __launch_bounds__(256) void reduce_loss(const float* __restrict__ partials,
                                                   float* __restrict__ out,
                                                   int n, float scale){
  __shared__ float red[4];
  int tid = threadIdx.x;
  float s = 0.f;
  for (int i = tid; i < n; i += 256) s += partials[i];
  s += __shfl_xor(s, 1);
  s += __shfl_xor(s, 2);
  s += __shfl_xor(s, 4);
  s += __shfl_xor(s, 8);
  s += __shfl_xor(s, 16);
  s += __shfl_xor(s, 32);
  if ((tid & 63) == 0) red[tid >> 6] = s;
  __syncthreads();
  if (tid == 0) out[0] = (red[0] + red[1] + red[2] + red[3]) * scale;
}

// ---------------- fallback pair kernel (ws too small) ----------
__global__ __launch_bounds__(256, 2) void pair_loss_mfma(const u16* __restrict__ hn,
                                                         const int* __restrict__ anchors,
                                                         const int* __restrict__ positives,
                                                         const int* __restrict__ negs,
                                                         float* __restrict__ out,
                                                         int P16, float scale){
  int lane = threadIdx.x & 63;
  int q = lane >> 4, i = lane & 15;
  int wid = blockIdx.x*(blockDim.x >> 6) + (threadIdx.x >> 6);
  int nw = gridDim.x * (blockDim.x >> 6);
  bool isdiag = (q == (i >> 2));
  int regsel = i & 3;
  float wsum = 0.f;
  for (int grp = wid; grp < P16; grp += nw){
    int p = grp*16 + i;
    int a = anchors[p];
    const u16* arow = hn + (size_t)a * PD_DIM;
    short8 af[4];
#pragma unroll
    for (int m = 0; m < 4; m++) af[m] = *(const short8*)(arow + m*32 + q*8);
    float runm = -1e30f, runs = 0.f, l0 = 0.f;
#pragma unroll
    for (int j = 0; j < 11; j++){
      int o = (j == 0) ? positives[p] : negs[p*10 + (j-1)];
      const u16* orow = hn + (size_t)o * PD_DIM;
      floatx4 acc = (floatx4){0.f, 0.f, 0.f, 0.f};
#pragma unroll
      for (int m = 0; m < 4; m++){
        short8 bf8 = *(const short8*)(orow + m*32 + q*8);
        acc = __builtin_amdgcn_mfma_f32_16x16x32_bf16(af[m], bf8, acc, 0, 0, 0);
      }
      float v = acc[regsel] * 2.0f;
      if (j == 0) l0 = v;
      float nm = fmaxf(runm, v);
      runs = runs * __expf(runm - nm) + __expf(v - nm);
      runm = nm;
    }
    wsum += isdiag ? ((runm + __logf(runs)) - l0) : 0.f;
  }
  wsum += __shfl_xor(wsum, 1);
  wsum += __shfl_xor(wsum, 2);
  wsum += __shfl_xor(wsum, 4);
  wsum += __shfl_xor(wsum, 8);
  wsum += __shfl_xor(wsum, 16);
  wsum += __shfl_xor(wsum, 32);
  if (lane == 0) atomicAdd(out, wsum * scale);
}

extern "C" void kernel_launch(void* const* d_in, const int* in_sizes, int n_in,
                              void* d_out, int out_size, void* d_ws, size_t ws_size,
                              hipStream_t stream){
  const float* x  = (const float*)d_in[0];
  const float* w1 = (const float*)d_in[1];
  const float* w2 = (const float*)d_in[2];
  const int* anchors   = (const int*)d_in[4];
  const int* positives = (const int*)d_in[5];
  const int* negidx    = (const int*)d_in[6];
  int P = in_sizes[4];
  float* out = (float*)d_out;

  u16* hn   = (u16*)d_ws;                  // 8192*128 bf16 (2 MB)
  u16* x_b  = hn   + 1048576;              // 8192*512
  u16* w1_b = x_b  + 4194304;              // 512*512
  u16* w2_b = w1_b + 262144;               // 128*512
  u16* h1_b = w2_b + 65536;                // 8192*512
  u8* sim   = (u8*)x_b;                    // 8192*8192 fp8 (67 MB, overlays x_b..)
  float* partials = (float*)((char*)d_ws + (size_t)1048576*2 + (size_t)8192*8192);

  const int NRUNS = 8160;
  const size_t need_sim = (size_t)1048576*2 + (size_t)8192*8192 + NRUNS*4;

  cvt_all<<<4416, 256, 0, stream>>>(x, w1, w2, x_b, w1_b, w2_b);
  gemm1_relu<<<dim3(128, 8), 256, 0, stream>>>(x_b, w1_b, h1_b);
  gemm2_norm<<<256, 256, 0, stream>>>(h1_b, w2_b, hn);

  if (ws_size >= need_sim){
    sim_gemm<<<dim3(64, 64), 256, 0, stream>>>(hn, sim);
    pair_lse<<<NRUNS, 256, 0, stream>>>(sim, negidx, partials);
    reduce_loss<<<1, 256, 0, stream>>>(partials, out, NRUNS, 1.0f/(float)P);
  } else {
    hipMemsetAsync(out, 0, sizeof(float), stream);
    pair_loss_mfma<<<2048, 256, 0, stream>>>(hn, anchors, positives, negidx,
                                             out, P/16, 1.0f/(float)P);
  }
}

// Round 19
// 167.457 us; speedup vs baseline: 1.2028x; 1.2028x over previous
//
#include <hip/hip_runtime.h>
#include <hip/hip_fp8.h>

typedef __attribute__((ext_vector_type(8))) short short8;
typedef __attribute__((ext_vector_type(4))) float floatx4;
typedef _Float16 half_t;
typedef unsigned short u16;
typedef unsigned char u8;
typedef unsigned int u32;
typedef unsigned long long u64;
typedef __attribute__((ext_vector_type(4))) unsigned short ushort4v;
typedef __attribute__((ext_vector_type(4))) u32 uint4v;

#define D_DIM 512
#define PD_DIM 128

// async global->LDS DMA, 16 B per lane. LDS dest = wave-uniform base + lane*16.
typedef __attribute__((address_space(3))) u32 lds_u32;
typedef const __attribute__((address_space(1))) u32 gbl_u32;
__device__ __forceinline__ void cp16(void* lds_base_wave_uniform, const void* g_per_lane){
#if __has_builtin(__builtin_amdgcn_global_load_lds)
  __builtin_amdgcn_global_load_lds((gbl_u32*)g_per_lane,
                                   (lds_u32*)lds_base_wave_uniform,
                                   16, 0, 0);
#else
  int lane = threadIdx.x & 63;
  ((float4*)lds_base_wave_uniform)[lane] = *(const float4*)((const char*)g_per_lane);
#endif
}

__device__ __forceinline__ u16 f2bf(float f){
  u32 u = __builtin_bit_cast(u32, f);
  u += 0x7fffu + ((u >> 16) & 1u);
  return (u16)(u >> 16);
}

__device__ __forceinline__ u8 f2fp8_sw(float f){
  __hip_fp8_e4m3 q(f);
  return (u8)q.__x;
}
__device__ __forceinline__ float fp82f(u8 b){
  __hip_fp8_e4m3 q;
  q.__x = (__hip_fp8_storage_t)b;
  return (float)q;
}

// HW packed f32->fp8(e4m3 OCP on gfx950): 2 instrs per 4 values.
__device__ __forceinline__ u32 pack4_fp8(float v0, float v1, float v2, float v3){
#if __has_builtin(__builtin_amdgcn_cvt_pk_fp8_f32)
  u32 r = 0;
  r = __builtin_amdgcn_cvt_pk_fp8_f32(v0, v1, r, false);  // bytes 0,1
  r = __builtin_amdgcn_cvt_pk_fp8_f32(v2, v3, r, true);   // bytes 2,3
  return r;
#else
  return (u32)f2fp8_sw(v0) | ((u32)f2fp8_sw(v1) << 8) |
         ((u32)f2fp8_sw(v2) << 16) | ((u32)f2fp8_sw(v3) << 24);
#endif
}

// fused f32->bf16 conversion for x (1048576 f4), w1 (65536 f4), w2 (16384 f4)
__global__ void cvt_all(const float* __restrict__ x, const float* __restrict__ w1,
                        const float* __restrict__ w2, u16* __restrict__ xb,
                        u16* __restrict__ w1b, u16* __restrict__ w2b){
  int i = blockIdx.x * blockDim.x + threadIdx.x;
  const float* s; u16* d; int off;
  if (i < 1048576)      { s = x;  d = xb;  off = i; }
  else if (i < 1114112) { s = w1; d = w1b; off = i - 1048576; }
  else if (i < 1130496) { s = w2; d = w2b; off = i - 1114112; }
  else return;
  float4 v = ((const float4*)s)[off];
  u16 o0 = f2bf(v.x), o1 = f2bf(v.y), o2 = f2bf(v.z), o3 = f2bf(v.w);
  ((u32*)d)[off*2]   = (u32)o0 | ((u32)o1 << 16);
  ((u32*)d)[off*2+1] = (u32)o2 | ((u32)o3 << 16);
}

// C[m,n] = relu(sum_k A[m,k]*B[n,k]) -> bf16. A:8192x512, B:512x512.
// 64x64 tile, BK=128, XOR-swizzled DMA staging (rounds 12/17).
__global__ __launch_bounds__(256) void gemm1_relu(const u16* __restrict__ A,
                                                  const u16* __restrict__ Bm,
                                                  u16* __restrict__ C){
  __shared__ __align__(16) u16 As[64*128];   // 16 KB (1024 chunks of 16 B)
  __shared__ __align__(16) u16 Bs[64*128];   // 16 KB
  int tid = threadIdx.x;
  int m0 = blockIdx.x * 64, n0 = blockIdx.y * 64;
  int w = tid >> 6, lane = tid & 63;
  int wy = w >> 1, wx = w & 1;               // wave tile: 32 x 32
  int mrow = lane & 15, kg = lane >> 4;
  floatx4 acc[2][2];
#pragma unroll
  for (int mt = 0; mt < 2; mt++)
#pragma unroll
    for (int nt = 0; nt < 2; nt++)
      acc[mt][nt] = (floatx4){0.f, 0.f, 0.f, 0.f};

  for (int k0 = 0; k0 < D_DIM; k0 += 128){
    __syncthreads();
#pragma unroll
    for (int i = 0; i < 4; i++){
      int c = tid + 256*i;
      int row = c >> 4, slot = c & 15;
      int gs = slot ^ (row & 7);
      cp16((char*)As + i*4096 + w*1024,
           (const char*)(A + (size_t)(m0+row)*D_DIM + k0) + gs*16);
      cp16((char*)Bs + i*4096 + w*1024,
           (const char*)(Bm + (size_t)(n0+row)*D_DIM + k0) + gs*16);
    }
    __syncthreads();
    int rx = mrow & 7;
#pragma unroll
    for (int s = 0; s < 4; s++){
      int lslot = (s*4 + kg) ^ rx;
      short8 af[2], bfr[2];
#pragma unroll
      for (int mt = 0; mt < 2; mt++)
        af[mt]  = *(const short8*)&As[(wy*32 + mt*16 + mrow)*128 + lslot*8];
#pragma unroll
      for (int nt = 0; nt < 2; nt++)
        bfr[nt] = *(const short8*)&Bs[(wx*32 + nt*16 + mrow)*128 + lslot*8];
#pragma unroll
      for (int mt = 0; mt < 2; mt++)
#pragma unroll
        for (int nt = 0; nt < 2; nt++)
          acc[mt][nt] = __builtin_amdgcn_mfma_f32_16x16x32_bf16(bfr[nt], af[mt], acc[mt][nt], 0, 0, 0);
    }
  }
#pragma unroll
  for (int mt = 0; mt < 2; mt++){
    int m = m0 + wy*32 + mt*16 + mrow;
#pragma unroll
    for (int nt = 0; nt < 2; nt++){
      int nchunk = n0 + wx*32 + nt*16 + kg*4;
      ushort4v pk;
#pragma unroll
      for (int i = 0; i < 4; i++){
        float v = acc[mt][nt][i];
        v = v > 0.f ? v : 0.f;
        pk[i] = f2bf(v);
      }
      *(ushort4v*)&C[(size_t)m*D_DIM + nchunk] = pk;
    }
  }
}

// Hn[m,:] = normalize(A[m,:] @ Bm^T) -> bf16. 32-row tiles, grid 256,
// BK=64 DMA+swizzle, Cs stride 132 (proven round 13).
__global__ __launch_bounds__(256) void gemm2_norm(const u16* __restrict__ A,
                                                  const u16* __restrict__ Bm,
                                                  u16* __restrict__ Hn){
  __shared__ __align__(16) char smem[20480];
  u16* As = (u16*)smem;            // 32 x 64 bf16 = 4 KB
  u16* Bs = (u16*)(smem + 4096);   // 128 x 64 bf16 = 16 KB
  float* Cs = (float*)smem;        // 32 x 132 f32 (reuse)
  int tid = threadIdx.x;
  int m0 = blockIdx.x * 32;
  int w = tid >> 6, lane = tid & 63;
  int wr = w & 1, wc = w >> 1;
  int mrow = lane & 15, kg = lane >> 4;
  floatx4 acc[4];
#pragma unroll
  for (int nt = 0; nt < 4; nt++) acc[nt] = (floatx4){0.f, 0.f, 0.f, 0.f};

  for (int k0 = 0; k0 < D_DIM; k0 += 64){
    __syncthreads();
    {
      int row = tid >> 3, slot = tid & 7;
      int gs = slot ^ (row & 7);
      cp16((char*)As + w*1024,
           (const char*)(A + (size_t)(m0+row)*D_DIM + k0) + gs*16);
    }
#pragma unroll
    for (int i = 0; i < 4; i++){
      int c = tid + 256*i;
      int row = c >> 3, slot = c & 7;
      int gs = slot ^ (row & 7);
      cp16((char*)Bs + i*4096 + w*1024,
           (const char*)(Bm + (size_t)row*D_DIM + k0) + gs*16);
    }
    __syncthreads();
    int rx = mrow & 7;
#pragma unroll
    for (int s = 0; s < 2; s++){
      int lslot = (s*4 + kg) ^ rx;
      short8 af = *(const short8*)&As[(wr*16 + mrow)*64 + lslot*8];
#pragma unroll
      for (int nt = 0; nt < 4; nt++){
        short8 bf8 = *(const short8*)&Bs[(wc*64 + nt*16 + mrow)*64 + lslot*8];
        acc[nt] = __builtin_amdgcn_mfma_f32_16x16x32_bf16(af, bf8, acc[nt], 0, 0, 0);
      }
    }
  }
  __syncthreads();
#pragma unroll
  for (int nt = 0; nt < 4; nt++){
    int cc = wc*64 + nt*16 + mrow;
#pragma unroll
    for (int i = 0; i < 4; i++)
      Cs[(wr*16 + kg*4 + i)*132 + cc] = acc[nt][i];
  }
  __syncthreads();
  int r = tid >> 3, seg = tid & 7;
  const float* rowp = Cs + r*132 + seg*16;
  float ssq = 0.f;
#pragma unroll
  for (int j = 0; j < 16; j++){ float v = rowp[j]; ssq += v*v; }
  ssq += __shfl_xor(ssq, 1);
  ssq += __shfl_xor(ssq, 2);
  ssq += __shfl_xor(ssq, 4);
  float rn = rsqrtf(fmaxf(ssq, 1e-24f));
  u32 pkw[8];
#pragma unroll
  for (int j = 0; j < 8; j++){
    float2 v = *(const float2*)(rowp + 2*j);
    pkw[j] = (u32)f2bf(v.x * rn) | ((u32)f2bf(v.y * rn) << 16);
  }
  u32* orow = (u32*)(Hn + (size_t)(m0 + r)*PD_DIM + seg*16);
  *(uint4v*)orow     = (uint4v){pkw[0], pkw[1], pkw[2], pkw[3]};
  *(uint4v*)(orow+4) = (uint4v){pkw[4], pkw[5], pkw[6], pkw[7]};
}

// S[m,n] = fp8_e4m3(2 * hn[m].hn[n]). REVERTED to round-16 proven form:
// 128x128 tile, single K-pass LDS-staged operands (DMA + XOR swizzle),
// LDS round-trip epilogue. Round-18's register-direct variant regressed
// 32->69 us: fragment loads span 16 rows -> 16 line-requests/instr,
// ~33M requests, gather-request-bound (the round-3 wall). LDS staging
// converts that to coalesced DMA + broadcast reuse -- it is load-bearing.
__global__ __launch_bounds__(256) void sim_gemm(const u16* __restrict__ A,
                                                u8* __restrict__ S){
  __shared__ __align__(16) u16 As[128*128];  // 32 KB (reused by epilogue)
  __shared__ __align__(16) u16 Bs[128*128];
  int tid = threadIdx.x;
  int m0 = blockIdx.x * 128, n0 = blockIdx.y * 128;
  int w = tid >> 6, lane = tid & 63;
  int wy = w >> 1, wx = w & 1;
  int mrow = lane & 15, kg = lane >> 4;

  const char* ga = (const char*)(A + (size_t)m0 * PD_DIM);
  const char* gb = (const char*)(A + (size_t)n0 * PD_DIM);
#pragma unroll
  for (int i = 0; i < 8; i++){
    int c = tid + 256*i;
    int row = c >> 4, slot = c & 15;
    int gchunk = row*16 + (slot ^ (row & 7));
    cp16((char*)As + i*4096 + w*1024, ga + gchunk*16);
    cp16((char*)Bs + i*4096 + w*1024, gb + gchunk*16);
  }
  __syncthreads();

  floatx4 acc[4][4];
#pragma unroll
  for (int mt = 0; mt < 4; mt++)
#pragma unroll
    for (int nt = 0; nt < 4; nt++)
      acc[mt][nt] = (floatx4){0.f, 0.f, 0.f, 0.f};

  int rx = mrow & 7;
#pragma unroll
  for (int s = 0; s < 4; s++){
    int lslot = (s*4 + kg) ^ rx;
    short8 af[4], bfr[4];
#pragma unroll
    for (int mt = 0; mt < 4; mt++)
      af[mt]  = *(const short8*)&As[(wy*64 + mt*16 + mrow)*128 + lslot*8];
#pragma unroll
    for (int nt = 0; nt < 4; nt++)
      bfr[nt] = *(const short8*)&Bs[(wx*64 + nt*16 + mrow)*128 + lslot*8];
#pragma unroll
    for (int mt = 0; mt < 4; mt++)
#pragma unroll
      for (int nt = 0; nt < 4; nt++)
        acc[mt][nt] = __builtin_amdgcn_mfma_f32_16x16x32_bf16(bfr[nt], af[mt], acc[mt][nt], 0, 0, 0);
  }

  // epilogue: fp8 tile -> padded LDS (stride 33 u32/row) -> coalesced 128-B
  // row-segment stores (dwordx4 per lane)
  __syncthreads();
  u32* lb = (u32*)As;                       // 128 rows x 33 u32
#pragma unroll
  for (int mt = 0; mt < 4; mt++){
    int m = wy*64 + mt*16 + mrow;
#pragma unroll
    for (int nt = 0; nt < 4; nt++){
      int ncol = wx*16 + nt*4 + kg;
      u32 pk = pack4_fp8(acc[mt][nt][0] * 2.0f, acc[mt][nt][1] * 2.0f,
                         acc[mt][nt][2] * 2.0f, acc[mt][nt][3] * 2.0f);
      lb[m*33 + ncol] = pk;
    }
  }
  __syncthreads();
#pragma unroll
  for (int i = 0; i < 4; i++){
    int c = tid + 256*i;
    int row = c >> 3, off = c & 7;
    const u32* src = lb + row*33 + off*4;
    uint4v v = (uint4v){src[0], src[1], src[2], src[3]};
    *(uint4v*)&S[(size_t)(m0+row)*8192 + n0 + off*16] = v;
  }
}

// One run per block; anchor row (8 KB fp8) in LDS; partials to global.
__global__ __launch_bounds__(256) void pair_lse(const u8* __restrict__ S,
                                                const int* __restrict__ negs,
                                                float* __restrict__ partials){
  __shared__ __align__(16) u8 row[8192];
  __shared__ float red[4];
  int tid = threadIdx.x;
  int g = blockIdx.x;
  int c = g / 255, r = g - c*255;
  int a = c + 32*r;
  const float4* src = (const float4*)(S + (size_t)a*8192);
  float4* dst = (float4*)row;
#pragma unroll
  for (int i = 0; i < 2; i++) dst[tid + 256*i] = src[tid + 256*i];
  __syncthreads();

  int len = 255 - r;
  size_t start = (size_t)c*32640 + (size_t)(r*(511 - r))/2;
  float lsum = 0.f;
  if (tid < len){
    size_t p = start + tid;
    int poscol = c + 32*(r + 1 + tid);
    float lg[11];
    lg[0] = fp82f(row[poscol]);
    const int2* np = (const int2*)(negs + p*10);
    int2 n0 = np[0], n1 = np[1], n2 = np[2], n3 = np[3], n4 = np[4];
    lg[1]  = fp82f(row[n0.x]);  lg[2]  = fp82f(row[n0.y]);
    lg[3]  = fp82f(row[n1.x]);  lg[4]  = fp82f(row[n1.y]);
    lg[5]  = fp82f(row[n2.x]);  lg[6]  = fp82f(row[n2.y]);
    lg[7]  = fp82f(row[n3.x]);  lg[8]  = fp82f(row[n3.y]);
    lg[9]  = fp82f(row[n4.x]);  lg[10] = fp82f(row[n4.y]);
    float s = 0.f;
#pragma unroll
    for (int j = 0; j < 11; j++) s += __expf(lg[j]);
    lsum = __logf(s) - lg[0];
  }
  lsum += __shfl_xor(lsum, 1);
  lsum += __shfl_xor(lsum, 2);
  lsum += __shfl_xor(lsum, 4);
  lsum += __shfl_xor(lsum, 8);
  lsum += __shfl_xor(lsum, 16);
  lsum += __shfl_xor(lsum, 32);
  int wv = tid >> 6;
  if ((tid & 63) == 0) red[wv] = lsum;
  __syncthreads();
  if (tid == 0) partials[g] = red[0] + red[1] + red[2] + red[3];
}

__global__ __launch_bounds__(256) void reduce_loss(const float* __restrict__ partials,
                                                   float* __restrict__ out,
                                                   int n, float scale){
  __shared__ float red[4];
  int tid = threadIdx.x;
  float s = 0.f;
  for (int i = tid; i < n; i += 256) s += partials[i];
  s += __shfl_xor(s, 1);
  s += __shfl_xor(s, 2);
  s += __shfl_xor(s, 4);
  s += __shfl_xor(s, 8);
  s += __shfl_xor(s, 16);
  s += __shfl_xor(s, 32);
  if ((tid & 63) == 0) red[tid >> 6] = s;
  __syncthreads();
  if (tid == 0) out[0] = (red[0] + red[1] + red[2] + red[3]) * scale;
}

// ---------------- fallback pair kernel (ws too small) ----------
__global__ __launch_bounds__(256, 2) void pair_loss_mfma(const u16* __restrict__ hn,
                                                         const int* __restrict__ anchors,
                                                         const int* __restrict__ positives,
                                                         const int* __restrict__ negs,
                                                         float* __restrict__ out,
                                                         int P16, float scale){
  int lane = threadIdx.x & 63;
  int q = lane >> 4, i = lane & 15;
  int wid = blockIdx.x*(blockDim.x >> 6) + (threadIdx.x >> 6);
  int nw = gridDim.x * (blockDim.x >> 6);
  bool isdiag = (q == (i >> 2));
  int regsel = i & 3;
  float wsum = 0.f;
  for (int grp = wid; grp < P16; grp += nw){
    int p = grp*16 + i;
    int a = anchors[p];
    const u16* arow = hn + (size_t)a * PD_DIM;
    short8 af[4];
#pragma unroll
    for (int m = 0; m < 4; m++) af[m] = *(const short8*)(arow + m*32 + q*8);
    float runm = -1e30f, runs = 0.f, l0 = 0.f;
#pragma unroll
    for (int j = 0; j < 11; j++){
      int o = (j == 0) ? positives[p] : negs[p*10 + (j-1)];
      const u16* orow = hn + (size_t)o * PD_DIM;
      floatx4 acc = (floatx4){0.f, 0.f, 0.f, 0.f};
#pragma unroll
      for (int m = 0; m < 4; m++){
        short8 bf8 = *(const short8*)(orow + m*32 + q*8);
        acc = __builtin_amdgcn_mfma_f32_16x16x32_bf16(af[m], bf8, acc, 0, 0, 0);
      }
      float v = acc[regsel] * 2.0f;
      if (j == 0) l0 = v;
      float nm = fmaxf(runm, v);
      runs = runs * __expf(runm - nm) + __expf(v - nm);
      runm = nm;
    }
    wsum += isdiag ? ((runm + __logf(runs)) - l0) : 0.f;
  }
  wsum += __shfl_xor(wsum, 1);
  wsum += __shfl_xor(wsum, 2);
  wsum += __shfl_xor(wsum, 4);
  wsum += __shfl_xor(wsum, 8);
  wsum += __shfl_xor(wsum, 16);
  wsum += __shfl_xor(wsum, 32);
  if (lane == 0) atomicAdd(out, wsum * scale);
}

extern "C" void kernel_launch(void* const* d_in, const int* in_sizes, int n_in,
                              void* d_out, int out_size, void* d_ws, size_t ws_size,
                              hipStream_t stream){
  const float* x  = (const float*)d_in[0];
  const float* w1 = (const float*)d_in[1];
  const float* w2 = (const float*)d_in[2];
  const int* anchors   = (const int*)d_in[4];
  const int* positives = (const int*)d_in[5];
  const int* negidx    = (const int*)d_in[6];
  int P = in_sizes[4];
  float* out = (float*)d_out;

  u16* hn   = (u16*)d_ws;                  // 8192*128 bf16 (2 MB)
  u16* x_b  = hn   + 1048576;              // 8192*512
  u16* w1_b = x_b  + 4194304;              // 512*512
  u16* w2_b = w1_b + 262144;               // 128*512
  u16* h1_b = w2_b + 65536;                // 8192*512
  u8* sim   = (u8*)x_b;                    // 8192*8192 fp8 (67 MB, overlays x_b..)
  float* partials = (float*)((char*)d_ws + (size_t)1048576*2 + (size_t)8192*8192);

  const int NRUNS = 8160;
  const size_t need_sim = (size_t)1048576*2 + (size_t)8192*8192 + NRUNS*4;

  cvt_all<<<4416, 256, 0, stream>>>(x, w1, w2, x_b, w1_b, w2_b);
  gemm1_relu<<<dim3(128, 8), 256, 0, stream>>>(x_b, w1_b, h1_b);
  gemm2_norm<<<256, 256, 0, stream>>>(h1_b, w2_b, hn);

  if (ws_size >= need_sim){
    sim_gemm<<<dim3(64, 64), 256, 0, stream>>>(hn, sim);
    pair_lse<<<NRUNS, 256, 0, stream>>>(sim, negidx, partials);
    reduce_loss<<<1, 256, 0, stream>>>(partials, out, NRUNS, 1.0f/(float)P);
  } else {
    hipMemsetAsync(out, 0, sizeof(float), stream);
    pair_loss_mfma<<<2048, 256, 0, stream>>>(hn, anchors, positives, negidx,
                                             out, P/16, 1.0f/(float)P);
  }
}